// Round 6
// baseline (578.887 us; speedup 1.0000x reference)
//
#include <hip/hip_runtime.h>
#include <math.h>

#define Bsz 128
#define Tsz 256
#define Isz 256
#define Hsz 256
#define Lsz 4
#define Ssz 3
#define Mrows (Bsz*Tsz)   // 32768

using f16x8 = __attribute__((ext_vector_type(8))) _Float16;
using f32x4 = __attribute__((ext_vector_type(4))) float;

__device__ inline float fast_sig(float x) { return 1.f / (1.f + __expf(-x)); }
__device__ inline float fast_tanh(float x) {
  const float e = __expf(-2.f * fabsf(x));
  const float y = (1.f - e) / (1.f + e);
  return x < 0.f ? -y : y;
}

// ---------------- fp32 -> fp16 convert (weights only) ----------------
__global__ __launch_bounds__(256) void f32_to_f16(
    const float* __restrict__ src, _Float16* __restrict__ dst, int n8)
{
  const int idx = blockIdx.x * 256 + threadIdx.x;
  if (idx >= n8) return;
  const float4 v0 = *(const float4*)(src + (size_t)idx * 8);
  const float4 v1 = *(const float4*)(src + (size_t)idx * 8 + 4);
  _Float16 h[8];
  h[0] = (_Float16)v0.x; h[1] = (_Float16)v0.y;
  h[2] = (_Float16)v0.z; h[3] = (_Float16)v0.w;
  h[4] = (_Float16)v1.x; h[5] = (_Float16)v1.y;
  h[6] = (_Float16)v1.z; h[7] = (_Float16)v1.w;
  *(uint4*)(dst + (size_t)idx * 8) = *(uint4*)h;
}

// ---------------- fused GRU-layer GEMM, fp16 MFMA, dbuf LDS ----------------
// gi_slab = A @ W_slab^T (slabs r/z/n), gating fused, h written fp16.
// grid: (M/128, 256/64, 3 cur). block 256 = 4 waves.
// AF32: A is fp32 (layer 0, x input) and converted during staging.
template<bool AF32>
__global__ __launch_bounds__(256, 2) void gemm_gru_f16(
    const float* __restrict__ Af,
    const _Float16* __restrict__ Ah_g, size_t a_cur_stride,
    const _Float16* __restrict__ Wbase, size_t w_cur_stride,
    const float* __restrict__ bi_g, size_t bi_stride,
    const float* __restrict__ bh_g, size_t bh_stride,
    _Float16* __restrict__ Hout)
{
  // 2 x (A 4160 + W 6336) fp16 = 20992 fp16 = 41984 B
  __shared__ _Float16 SB[20992];
  _Float16* const Ab[2] = { SB, SB + 4160 };
  _Float16* const Wb[2] = { SB + 8320, SB + 14656 };

  const int tid = threadIdx.x;
  const int cu  = blockIdx.z;
  const int m0  = blockIdx.x * 128;
  const int n0  = blockIdx.y * 64;

  const _Float16* A = AF32 ? nullptr : (Ah_g + (size_t)cu * a_cur_stride);
  const _Float16* W = Wbase + (size_t)cu * w_cur_stride;
  const float* bi = bi_g + (size_t)cu * bi_stride;
  const float* bh = bh_g + (size_t)cu * bh_stride;

  const int lane = tid & 63;
  const int wv   = tid >> 6;
  const int q    = lane >> 4;      // k-chunk within frag
  const int c    = lane & 15;      // row/col within frag
  const int mb   = wv * 32;        // wave's row base within 128-tile

  // staging indices (constant over k)
  const int ach  = tid & 3;                 // A/W k-chunk (8 fp16)
  const int arow0 = tid >> 2;               // A rows: arow0, arow0+64
  const int wrr  = (tid >> 2) & 63;         // W row within 64-tile

  const size_t aoff0 = (size_t)(m0 + arow0) * 256 + ach * 8;
  const size_t aoff1 = (size_t)(m0 + arow0 + 64) * 256 + ach * 8;
  size_t woff[3];
  #pragma unroll
  for (int s = 0; s < 3; s++)
    woff[s] = (size_t)(s * 256 + n0 + wrr) * 256 + ach * 8;
  const int alds0 = (ach * 130 + arow0) * 8;
  const int alds1 = (ach * 130 + arow0 + 64) * 8;
  int wlds[3];
  #pragma unroll
  for (int s = 0; s < 3; s++) wlds[s] = ((s * 4 + ach) * 66 + wrr) * 8;

  f32x4 acc[3][2][4];
  #pragma unroll
  for (int s = 0; s < 3; s++)
    #pragma unroll
    for (int mi = 0; mi < 2; mi++)
      #pragma unroll
      for (int ni = 0; ni < 4; ni++)
        acc[s][mi][ni] = (f32x4)0.f;

  uint4 pa[2]; float4 paf[2][2]; uint4 pw[3];

  // ---- prologue: load k=0, write buf 0 ----
  if (AF32) {
    #pragma unroll
    for (int i = 0; i < 2; i++) {
      const size_t g = (i ? aoff1 : aoff0);
      paf[i][0] = *(const float4*)(Af + g);
      paf[i][1] = *(const float4*)(Af + g + 4);
    }
  } else {
    pa[0] = *(const uint4*)(A + aoff0);
    pa[1] = *(const uint4*)(A + aoff1);
  }
  #pragma unroll
  for (int s = 0; s < 3; s++) pw[s] = *(const uint4*)(W + woff[s]);

  if (AF32) {
    #pragma unroll
    for (int i = 0; i < 2; i++) {
      _Float16 hh[8];
      hh[0] = (_Float16)paf[i][0].x; hh[1] = (_Float16)paf[i][0].y;
      hh[2] = (_Float16)paf[i][0].z; hh[3] = (_Float16)paf[i][0].w;
      hh[4] = (_Float16)paf[i][1].x; hh[5] = (_Float16)paf[i][1].y;
      hh[6] = (_Float16)paf[i][1].z; hh[7] = (_Float16)paf[i][1].w;
      *(uint4*)&Ab[0][i ? alds1 : alds0] = *(uint4*)hh;
    }
  } else {
    *(uint4*)&Ab[0][alds0] = pa[0];
    *(uint4*)&Ab[0][alds1] = pa[1];
  }
  #pragma unroll
  for (int s = 0; s < 3; s++) *(uint4*)&Wb[0][wlds[s]] = pw[s];
  __syncthreads();

  // ---- K loop: single barrier per step, prefetch overlaps MFMA ----
  for (int k = 0; k < 8; k++) {
    const int cb = k & 1;
    if (k < 7) {
      const int kc = (k + 1) * 32;
      if (AF32) {
        #pragma unroll
        for (int i = 0; i < 2; i++) {
          const size_t g = (i ? aoff1 : aoff0) + kc;
          paf[i][0] = *(const float4*)(Af + g);
          paf[i][1] = *(const float4*)(Af + g + 4);
        }
      } else {
        pa[0] = *(const uint4*)(A + aoff0 + kc);
        pa[1] = *(const uint4*)(A + aoff1 + kc);
      }
      #pragma unroll
      for (int s = 0; s < 3; s++) pw[s] = *(const uint4*)(W + woff[s] + kc);
    }

    const _Float16* Ac = Ab[cb];
    const _Float16* Wc = Wb[cb];
    const f16x8 a0 = *(const f16x8*)&Ac[(q * 130 + mb + c) * 8];
    const f16x8 a1 = *(const f16x8*)&Ac[(q * 130 + mb + 16 + c) * 8];
    #pragma unroll
    for (int s = 0; s < 3; s++) {
      #pragma unroll
      for (int ni = 0; ni < 4; ni++) {
        const f16x8 w = *(const f16x8*)&Wc[((s * 4 + q) * 66 + ni * 16 + c) * 8];
        acc[s][0][ni] = __builtin_amdgcn_mfma_f32_16x16x32_f16(a0, w, acc[s][0][ni], 0, 0, 0);
        acc[s][1][ni] = __builtin_amdgcn_mfma_f32_16x16x32_f16(a1, w, acc[s][1][ni], 0, 0, 0);
      }
    }

    if (k < 7) {
      _Float16* An = Ab[cb ^ 1];
      _Float16* Wn = Wb[cb ^ 1];
      if (AF32) {
        #pragma unroll
        for (int i = 0; i < 2; i++) {
          _Float16 hh[8];
          hh[0] = (_Float16)paf[i][0].x; hh[1] = (_Float16)paf[i][0].y;
          hh[2] = (_Float16)paf[i][0].z; hh[3] = (_Float16)paf[i][0].w;
          hh[4] = (_Float16)paf[i][1].x; hh[5] = (_Float16)paf[i][1].y;
          hh[6] = (_Float16)paf[i][1].z; hh[7] = (_Float16)paf[i][1].w;
          *(uint4*)&An[i ? alds1 : alds0] = *(uint4*)hh;
        }
      } else {
        *(uint4*)&An[alds0] = pa[0];
        *(uint4*)&An[alds1] = pa[1];
      }
      #pragma unroll
      for (int s = 0; s < 3; s++) *(uint4*)&Wn[wlds[s]] = pw[s];
      __syncthreads();
    }
  }

  // ---- epilogue: gating -> LDS transpose -> coalesced b128 stores ----
  float bir[4], biz[4], bin_[4], bhr[4], bhz[4], bhn[4];
  #pragma unroll
  for (int ni = 0; ni < 4; ni++) {
    const int n = n0 + ni * 16 + c;
    bir[ni]  = bi[n];       bhr[ni] = bh[n];
    biz[ni]  = bi[256 + n]; bhz[ni] = bh[256 + n];
    bin_[ni] = bi[512 + n]; bhn[ni] = bh[512 + n];
  }
  _Float16 hv[2][4][4];   // [mi][reg][ni]
  #pragma unroll
  for (int mi = 0; mi < 2; mi++)
    #pragma unroll
    for (int reg = 0; reg < 4; reg++)
      #pragma unroll
      for (int ni = 0; ni < 4; ni++) {
        const float gr = acc[0][mi][ni][reg] + bir[ni] + bhr[ni];
        const float gz = acc[1][mi][ni][reg] + biz[ni] + bhz[ni];
        const float gn = acc[2][mi][ni][reg] + bin_[ni];
        const float r  = fast_sig(gr);
        const float zz = fast_sig(gz);
        const float nn = fast_tanh(gn + r * bhn[ni]);
        hv[mi][reg][ni] = (_Float16)((1.f - zz) * nn);
      }
  __syncthreads();   // all staging reads done; reuse SB as transpose area
  // transpose layout: [m][n], stride 80 fp16 (160 B -> 16B-aligned rows)
  #pragma unroll
  for (int mi = 0; mi < 2; mi++)
    #pragma unroll
    for (int reg = 0; reg < 4; reg++) {
      const int m = mb + mi * 16 + q * 4 + reg;
      #pragma unroll
      for (int ni = 0; ni < 4; ni++)
        SB[m * 80 + ni * 16 + c] = hv[mi][reg][ni];
    }
  __syncthreads();
  {
    const int r = tid >> 1, part = tid & 1;     // 2 threads/row, 32 fp16 each
    const size_t gb = ((size_t)cu * Mrows + m0 + r) * 256 + n0 + part * 32;
    const _Float16* src = &SB[r * 80 + part * 32];
    #pragma unroll
    for (int i = 0; i < 4; i++)
      *(uint4*)(Hout + gb + i * 8) = *(const uint4*)(src + i * 8);
  }
}

// ---------------- per-layer dot products (e, p), block-tiled ----------------
__global__ __launch_bounds__(256) void ep_tile(
    const _Float16* __restrict__ Hh,
    const float* __restrict__ w_lw, const float* __restrict__ w_sel, int layer,
    float* __restrict__ e, float* __restrict__ p)
{
  __shared__ _Float16 hs[64 * 264];
  __shared__ float wc[7][256];
  __shared__ float ps[4][64][8];
  const int tid = threadIdx.x;
  const size_t mg0 = (size_t)blockIdx.x * 64;

  #pragma unroll
  for (int i = 0; i < 8; i++) {
    const int ci = tid + i * 256;
    const int row = ci >> 5, kc = ci & 31;
    *(uint4*)&hs[row * 264 + kc * 8] =
        *(const uint4*)(Hh + (mg0 + row) * 256 + kc * 8);
  }
  #pragma unroll
  for (int j = 0; j < 7; j++)
    wc[j][tid] = (j < 4) ? w_lw[j * 256 + tid] : w_sel[(j - 4) * 512 + tid];
  __syncthreads();

  const int r = tid & 63, pp = tid >> 6;
  float acc[7] = {0.f, 0.f, 0.f, 0.f, 0.f, 0.f, 0.f};
  #pragma unroll
  for (int i = 0; i < 8; i++) {
    union { uint4 u; _Float16 h[8]; } hvv;
    hvv.u = *(uint4*)&hs[r * 264 + pp * 64 + i * 8];
    float hf[8];
    #pragma unroll
    for (int k = 0; k < 8; k++) hf[k] = (float)hvv.h[k];
    #pragma unroll
    for (int j = 0; j < 7; j++) {
      const float4 w0 = *(const float4*)&wc[j][pp * 64 + i * 8];
      const float4 w1 = *(const float4*)&wc[j][pp * 64 + i * 8 + 4];
      acc[j] += hf[0] * w0.x + hf[1] * w0.y + hf[2] * w0.z + hf[3] * w0.w
              + hf[4] * w1.x + hf[5] * w1.y + hf[6] * w1.z + hf[7] * w1.w;
    }
  }
  #pragma unroll
  for (int j = 0; j < 7; j++) ps[pp][r][j] = acc[j];
  __syncthreads();

  if (tid < 64) {
    float d[7];
    #pragma unroll
    for (int j = 0; j < 7; j++)
      d[j] = ps[0][tid][j] + ps[1][tid][j] + ps[2][tid][j] + ps[3][tid][j];
    const size_t mg = mg0 + tid;
    const int cc = (int)(mg >> 15);
    const int m  = (int)(mg & 32767);
    const int b = m >> 8, t = m & 255;
    const size_t base = ((size_t)cc * Tsz + t) * Bsz + b;
    #pragma unroll
    for (int j = 0; j < 4; j++) e[base * 16 + layer * 4 + j] = d[j];
    #pragma unroll
    for (int j = 0; j < 3; j++) p[base * 12 + layer * 3 + j] = d[4 + j];
  }
}

// ---------------- softmax-attention + batch-reduced selector scores ----------------
__global__ __launch_bounds__(128) void attn_finish(
    const float* __restrict__ e, const float* __restrict__ p,
    const float* __restrict__ hidden, const float* __restrict__ b_lw,
    float* __restrict__ score_h)
{
  const int t = blockIdx.x, cc = blockIdx.y;
  const int b = threadIdx.x;
  const float* eb = e + ((size_t)(cc * Tsz + t) * Bsz + b) * 16;
  const float* pb = p + ((size_t)(cc * Tsz + t) * Bsz + b) * 12;
  const float* hb = hidden + b * 16;
  const float bl0 = b_lw[0], bl1 = b_lw[1], bl2 = b_lw[2], bl3 = b_lw[3];
  float attn[4];
  #pragma unroll
  for (int i = 0; i < 4; i++) {
    attn[i] = hb[i * 4 + 0] * (eb[i * 4 + 0] + bl0)
            + hb[i * 4 + 1] * (eb[i * 4 + 1] + bl1)
            + hb[i * 4 + 2] * (eb[i * 4 + 2] + bl2)
            + hb[i * 4 + 3] * (eb[i * 4 + 3] + bl3);
  }
  const float mx = fmaxf(fmaxf(attn[0], attn[1]), fmaxf(attn[2], attn[3]));
  float ex[4], sum = 0.f;
  #pragma unroll
  for (int i = 0; i < 4; i++) { ex[i] = expf(attn[i] - mx); sum += ex[i]; }
  const float inv = 1.f / sum;
  float sc[3];
  #pragma unroll
  for (int s = 0; s < 3; s++) {
    float v = 0.f;
    #pragma unroll
    for (int i = 0; i < 4; i++) v += ex[i] * pb[i * 3 + s];
    sc[s] = v * inv;
  }
  #pragma unroll
  for (int off = 32; off; off >>= 1)
    #pragma unroll
    for (int s = 0; s < 3; s++) sc[s] += __shfl_xor(sc[s], off);
  __shared__ float red[2][3];
  const int wv = threadIdx.x >> 6, ln = threadIdx.x & 63;
  if (ln == 0) { red[wv][0] = sc[0]; red[wv][1] = sc[1]; red[wv][2] = sc[2]; }
  __syncthreads();
  if (threadIdx.x == 0) {
    #pragma unroll
    for (int s = 0; s < 3; s++)
      score_h[((size_t)cc * Tsz + t) * 3 + s] = red[0][s] + red[1][s];
  }
}

// ---------------- xs[t,s] ----------------
__global__ __launch_bounds__(256) void xs_kernel(
    const float* __restrict__ x, const float* __restrict__ w_sel,
    const float* __restrict__ b_sel, float* __restrict__ xs)
{
  const int t = blockIdx.x, k = threadIdx.x;
  float s = 0.f;
  for (int b = 0; b < Bsz; b++) s += x[((size_t)b * Tsz + t) * Isz + k];
  float pr[3];
  #pragma unroll
  for (int qq = 0; qq < 3; qq++) pr[qq] = s * w_sel[qq * (Hsz + Isz) + Hsz + k];
  #pragma unroll
  for (int off = 32; off; off >>= 1)
    #pragma unroll
    for (int qq = 0; qq < 3; qq++) pr[qq] += __shfl_xor(pr[qq], off);
  __shared__ float red[4][3];
  const int wv = k >> 6, ln = k & 63;
  if (ln == 0) { red[wv][0] = pr[0]; red[wv][1] = pr[1]; red[wv][2] = pr[2]; }
  __syncthreads();
  if (k == 0) {
    #pragma unroll
    for (int qq = 0; qq < 3; qq++)
      xs[t * 3 + qq] = red[0][qq] + red[1][qq] + red[2][qq] + red[3][qq]
                      + (float)Bsz * b_sel[qq];
  }
}

// ---------------- serial selector chain ----------------
__global__ __launch_bounds__(256) void select_kernel(
    const float* __restrict__ score_h, const float* __restrict__ xs,
    int* __restrict__ cur)
{
  __shared__ int f[Tsz][3];
  const int tid = threadIdx.x;
  for (int u = tid; u < (Tsz - 1) * 3; u += 256) {
    const int t = 1 + u / 3, cc = u % 3;
    const float* sh = score_h + ((size_t)cc * Tsz + (t - 1)) * 3;
    const float* xr = xs + t * 3;
    const float v0 = sh[0] + xr[0];
    const float v1 = sh[1] + xr[1];
    const float v2 = sh[2] + xr[2];
    int best = 0; float bv = v0;
    if (v1 > bv) { bv = v1; best = 1; }
    if (v2 > bv) { bv = v2; best = 2; }
    f[t][cc] = best;
  }
  __syncthreads();
  if (tid == 0) {
    int cc = 0; cur[0] = 0;
    for (int t = 1; t < Tsz; t++) { cc = f[t][cc]; cur[t] = cc; }
  }
}

// ---------------- gather outputs (fp16 h -> fp32 out) ----------------
__global__ __launch_bounds__(256) void gather_out(
    const _Float16* __restrict__ Hh, const int* __restrict__ cur,
    float* __restrict__ out)
{
  const size_t idx = ((size_t)blockIdx.x * 256 + threadIdx.x) * 4;
  const size_t BTH = (size_t)Bsz * Tsz * Hsz;
  int b, t, h;
  if (idx < BTH) {
    b = (int)(idx >> 16);
    const int rem = (int)(idx & 65535);
    t = rem >> 8; h = rem & 255;
  } else {
    const size_t r2 = idx - BTH;
    b = (int)(r2 >> 8); h = (int)(r2 & 255); t = Tsz - 1;
  }
  const int cc = cur[t];
  const size_t g = (((size_t)cc * Mrows + (size_t)b * Tsz + t) * Hsz + h);
  union { ushort4 u; _Float16 hv[4]; } cv;
  cv.u = *(const ushort4*)(Hh + g);
  float4 v;
  v.x = (float)cv.hv[0]; v.y = (float)cv.hv[1];
  v.z = (float)cv.hv[2]; v.w = (float)cv.hv[3];
  *(float4*)(out + idx) = v;
}

extern "C" void kernel_launch(void* const* d_in, const int* in_sizes, int n_in,
                              void* d_out, int out_size, void* d_ws, size_t ws_size,
                              hipStream_t stream) {
  const float* x      = (const float*)d_in[0];
  const float* hidden = (const float*)d_in[1];
  const float* w_ih0  = (const float*)d_in[2];
  const float* b_ih0  = (const float*)d_in[3];
  const float* b_hh0  = (const float*)d_in[4];
  const float* w_ih   = (const float*)d_in[5];
  const float* b_ih   = (const float*)d_in[6];
  const float* b_hh   = (const float*)d_in[7];
  const float* w_lw   = (const float*)d_in[8];
  const float* b_lw   = (const float*)d_in[9];
  const float* w_sel  = (const float*)d_in[10];
  const float* b_sel  = (const float*)d_in[11];
  float* out = (float*)d_out;

  char* w = (char*)d_ws;
  const size_t HN = (size_t)3 * Mrows * 256;       // 25.2M
  const size_t W0N = (size_t)3 * 768 * 256;        // 589824
  const size_t WLN = (size_t)3 * 3 * 768 * 256;    // 1769472
  _Float16* HA  = (_Float16*)w; w += HN * 2;
  _Float16* HB  = (_Float16*)w; w += HN * 2;
  _Float16* Wh0 = (_Float16*)w; w += W0N * 2;
  _Float16* WhL = (_Float16*)w; w += WLN * 2;
  float* e       = (float*)w; w += (size_t)3 * Tsz * Bsz * 16 * 4;
  float* p       = (float*)w; w += (size_t)3 * Tsz * Bsz * 12 * 4;
  float* score_h = (float*)w; w += (size_t)3 * Tsz * 3 * 4;
  float* xsb     = (float*)w; w += (size_t)Tsz * 3 * 4;
  int*   curb    = (int*)w;   w += (size_t)Tsz * 4;

  // fp32 -> fp16 weight conversions
  f32_to_f16<<<(int)(W0N / 8 + 255) / 256, 256, 0, stream>>>(w_ih0, Wh0, (int)(W0N / 8));
  f32_to_f16<<<(int)(WLN / 8 + 255) / 256, 256, 0, stream>>>(w_ih, WhL, (int)(WLN / 8));

  dim3 ggrid(Mrows / 128, 4, 3);

  // layer 0: A = x (fp32, converted in-kernel, shared across cur)
  gemm_gru_f16<true><<<ggrid, 256, 0, stream>>>(
      x, nullptr, (size_t)0, Wh0, (size_t)768 * 256,
      b_ih0, (size_t)768, b_hh0, (size_t)768, HA);
  ep_tile<<<(3 * Mrows) / 64, 256, 0, stream>>>(HA, w_lw, w_sel, 0, e, p);

  const size_t wcur = (size_t)3 * 768 * 256;
  const size_t bst  = (size_t)3 * 768;
  _Float16* ping = HA; _Float16* pong = HB;
  for (int l = 1; l < 4; l++) {
    gemm_gru_f16<false><<<ggrid, 256, 0, stream>>>(
        nullptr, ping, (size_t)Mrows * 256,
        WhL + (size_t)(l - 1) * 768 * 256, wcur,
        b_ih + (size_t)(l - 1) * 768, bst,
        b_hh + (size_t)(l - 1) * 768, bst, pong);
    ep_tile<<<(3 * Mrows) / 64, 256, 0, stream>>>(pong, w_lw, w_sel, l, e, p);
    _Float16* t1 = ping; ping = pong; pong = t1;
  }

  attn_finish<<<dim3(Tsz, 3), 128, 0, stream>>>(e, p, hidden, b_lw, score_h);
  xs_kernel<<<Tsz, 256, 0, stream>>>(x, w_sel, b_sel, xsb);
  select_kernel<<<1, 256, 0, stream>>>(score_h, xsb, curb);
  gather_out<<<8224, 256, 0, stream>>>(ping, curb, out);
}